// Round 1
// baseline (349.599 us; speedup 1.0000x reference)
//
#include <hip/hip_runtime.h>
#include <hip/hip_bf16.h>

// ---- constants for this problem ----
// N=8192 tokens, DIM=1024, H=16, HKV=4, HD=64, B=8, S=1024

typedef __bf16 bf16x8 __attribute__((ext_vector_type(8)));
typedef float f32x4 __attribute__((ext_vector_type(4)));

__device__ __forceinline__ void async16(const void* g, void* l) {
  __builtin_amdgcn_global_load_lds((const __attribute__((address_space(1))) void*)g,
                                   (__attribute__((address_space(3))) void*)l, 16, 0, 0);
}

__device__ __forceinline__ unsigned short f2bfu(float x) {
  __hip_bfloat16 h = __float2bfloat16(x);
  return __builtin_bit_cast(unsigned short, h);
}
__device__ __forceinline__ float bfu2f(unsigned short u) {
  return __bfloat162float(__builtin_bit_cast(__hip_bfloat16, u));
}

// ---------------- fp32 -> bf16 cast (vectorized x4) ----------------
__global__ __launch_bounds__(256) void castk(const float4* __restrict__ src,
                                             ushort4* __restrict__ dst, int n4) {
  int i = blockIdx.x * 256 + threadIdx.x;
  if (i >= n4) return;
  float4 v = src[i];
  ushort4 o;
  o.x = f2bfu(v.x); o.y = f2bfu(v.y); o.z = f2bfu(v.z); o.w = f2bfu(v.w);
  dst[i] = o;
}

// ---------------- NT GEMM: C[M][N] = A[M][K] * B[N][K]^T (bf16 in, f32 out) ----------------
// 128x128 block tile, BK=32, 4 waves each computing 64x64 (4x4 of 16x16x32 MFMA).
__global__ __launch_bounds__(256) void gemm_bt(
    const __hip_bfloat16* __restrict__ A, const __hip_bfloat16* __restrict__ Bm,
    float* __restrict__ C, int M, int N, int K)
{
  __shared__ __align__(16) unsigned short As[128 * 32];
  __shared__ __align__(16) unsigned short Bs[128 * 32];
  const int tid = threadIdx.x;
  const int wave = tid >> 6, lane = tid & 63;
  const int quad = lane >> 4, l15 = lane & 15;
  const int bn = blockIdx.x, bm = blockIdx.y;
  const int wm = (wave >> 1) * 64, wn = (wave & 1) * 64;
  const int srow = lane >> 2, scol = (lane & 3) * 8;

  f32x4 acc[4][4] = {};

  const __hip_bfloat16* Ab = A + (size_t)bm * 128 * K;
  const __hip_bfloat16* Bb = Bm + (size_t)bn * 128 * K;

  for (int kt = 0; kt < K; kt += 32) {
    __syncthreads();
#pragma unroll
    for (int c = 0; c < 2; c++) {
      const int ch = wave * 2 + c;  // 8 chunks of 1KB per tile
      async16(Ab + (size_t)(ch * 16 + srow) * K + kt + scol, &As[ch * 512]);
      async16(Bb + (size_t)(ch * 16 + srow) * K + kt + scol, &Bs[ch * 512]);
    }
    __syncthreads();
    bf16x8 af[4], bfr[4];
#pragma unroll
    for (int mt = 0; mt < 4; mt++)
      af[mt] = *(const bf16x8*)&As[(wm + mt * 16 + l15) * 32 + quad * 8];
#pragma unroll
    for (int nt = 0; nt < 4; nt++)
      bfr[nt] = *(const bf16x8*)&Bs[(wn + nt * 16 + l15) * 32 + quad * 8];
#pragma unroll
    for (int mt = 0; mt < 4; mt++)
#pragma unroll
      for (int nt = 0; nt < 4; nt++)
        acc[mt][nt] = __builtin_amdgcn_mfma_f32_16x16x32_bf16(af[mt], bfr[nt], acc[mt][nt], 0, 0, 0);
  }

#pragma unroll
  for (int mt = 0; mt < 4; mt++)
#pragma unroll
    for (int nt = 0; nt < 4; nt++)
#pragma unroll
      for (int r = 0; r < 4; r++) {
        const int row = bm * 128 + wm + mt * 16 + quad * 4 + r;
        const int col = bn * 128 + wn + nt * 16 + l15;
        C[(size_t)row * N + col] = acc[mt][nt][r];
      }
}

// ---------------- per-token RMSNorm + RoPE + gain, emit bf16 Q/K ----------------
__global__ __launch_bounds__(256) void normrope(
    const float* __restrict__ c1, const float* __restrict__ cosb, const float* __restrict__ sinb,
    const float* __restrict__ qgain, const float* __restrict__ qscale, const float* __restrict__ kscale,
    __hip_bfloat16* __restrict__ Qo, __hip_bfloat16* __restrict__ Ko)
{
  const int t = blockIdx.x;
  const int wave = threadIdx.x >> 6, lane = threadIdx.x & 63;
  const float c = cosb[t * 32 + (lane & 31)];
  const float s = sinb[t * 32 + (lane & 31)];
  const float qs = qscale[0], ks = kscale[0];
  const float* row = c1 + (size_t)t * 1536;

#pragma unroll
  for (int i = 0; i < 5; i++) {
    // i<4: q head h = wave + i*4 ; i==4: k head h = wave
    const int h = (i < 4) ? (wave + i * 4) : wave;
    const float* src = (i < 4) ? (row + h * 64) : (row + 1024 + h * 64);
    float v = src[lane];
    float ss = v * v;
#pragma unroll
    for (int off = 1; off < 64; off <<= 1) ss += __shfl_xor(ss, off);
    const float inv = rsqrtf(ss * (1.0f / 64.0f) + 1.1920929e-07f);
    v *= inv * ((i < 4) ? qs : ks);
    const float p = __shfl_xor(v, 32);
    float r = (lane < 32) ? (v * c + p * s) : (v * c - p * s);
    if (i < 4) {
      r *= qgain[h];
      Qo[(size_t)t * 1024 + h * 64 + lane] = __float2bfloat16(r);
    } else {
      Ko[(size_t)t * 256 + h * 64 + lane] = __float2bfloat16(r);
    }
  }
}

// ---------------- transpose V slice of c1 into Vt[b][kvh][d][s] (bf16) ----------------
__global__ __launch_bounds__(256) void vtrans(const float* __restrict__ c1,
                                              __hip_bfloat16* __restrict__ Vt) {
  __shared__ float t[64][65];
  const int st = blockIdx.x, kvh = blockIdx.y, b = blockIdx.z;
  const int tid = threadIdx.x;
  const int s0 = st * 64;
#pragma unroll
  for (int i = 0; i < 16; i++) {
    const int idx = tid + i * 256;
    const int sl = idx >> 6, d = idx & 63;
    t[sl][d] = c1[(size_t)(b * 1024 + s0 + sl) * 1536 + 1280 + kvh * 64 + d];
  }
  __syncthreads();
#pragma unroll
  for (int i = 0; i < 16; i++) {
    const int idx = tid + i * 256;
    const int d = idx >> 6, sl = idx & 63;
    Vt[((size_t)(b * 4 + kvh) * 64 + d) * 1024 + s0 + sl] = __float2bfloat16(t[sl][d]);
  }
}

// ---------------- flash attention: block = (qtile, h, b), 4 waves, 64 q-rows ----------------
__global__ __launch_bounds__(256) void attn(
    const __hip_bfloat16* __restrict__ Q,   // [N][16][64]
    const __hip_bfloat16* __restrict__ Kk,  // [N][4][64]
    const __hip_bfloat16* __restrict__ Vt,  // [8][4][64][1024]
    __hip_bfloat16* __restrict__ Y)         // [N][16][64]
{
  __shared__ __align__(16) unsigned short Qs[64 * 64];
  __shared__ __align__(16) unsigned short Ks[64 * 64];
  __shared__ __align__(16) unsigned short Vs[64 * 64];   // [d][k]
  __shared__ __align__(16) unsigned short Ps[64 * 72];   // padded stride 72

  const int qt = blockIdx.x, h = blockIdx.y, b = blockIdx.z;
  const int tid = threadIdx.x;
  const int wave = tid >> 6, lane = tid & 63;
  const int quad = lane >> 4, l15 = lane & 15;
  const int kvh = h >> 2;
  const int tok0 = b * 1024 + qt * 64;
  const int qrow = lane >> 3, qcol = (lane & 7) * 8;

  // stage Q tile (8 chunks of 1KB)
#pragma unroll
  for (int c = 0; c < 2; c++) {
    const int ch = wave * 2 + c;
    async16(Q + (size_t)(tok0 + ch * 8 + qrow) * 1024 + h * 64 + qcol, &Qs[ch * 512]);
  }

  f32x4 of[4] = {};
  float mrow[4], lrow[4];
#pragma unroll
  for (int r = 0; r < 4; r++) { mrow[r] = -INFINITY; lrow[r] = 0.0f; }

  for (int kt = 0; kt <= qt; kt++) {
    __syncthreads();  // prior iteration done with Ks/Vs
#pragma unroll
    for (int c = 0; c < 2; c++) {
      const int ch = wave * 2 + c;
      async16(Kk + (size_t)(b * 1024 + kt * 64 + ch * 8 + qrow) * 256 + kvh * 64 + qcol,
              &Ks[ch * 512]);
      async16(Vt + ((size_t)((b * 4 + kvh) * 64 + ch * 8 + qrow)) * 1024 + kt * 64 + qcol,
              &Vs[ch * 512]);
    }
    __syncthreads();  // staging (and Q on first iter) complete

    // S = Q K^T for this wave's 16 rows x 64 cols
    f32x4 sf[4] = {};
#pragma unroll
    for (int kc = 0; kc < 2; kc++) {
      const bf16x8 aq = *(const bf16x8*)&Qs[(wave * 16 + l15) * 64 + kc * 32 + quad * 8];
#pragma unroll
      for (int nt = 0; nt < 4; nt++) {
        const bf16x8 bk = *(const bf16x8*)&Ks[(nt * 16 + l15) * 64 + kc * 32 + quad * 8];
        sf[nt] = __builtin_amdgcn_mfma_f32_16x16x32_bf16(aq, bk, sf[nt], 0, 0, 0);
      }
    }

    // scale + causal mask (only the diagonal tile needs masking)
    const bool diag = (kt == qt);
#pragma unroll
    for (int nt = 0; nt < 4; nt++)
#pragma unroll
      for (int r = 0; r < 4; r++) {
        float sv = sf[nt][r] * 0.125f;
        if (diag) {
          const int qi = wave * 16 + quad * 4 + r;
          const int ki = nt * 16 + l15;
          if (ki > qi) sv = -INFINITY;
        }
        sf[nt][r] = sv;
      }

    // online softmax (rows indexed by reg r within this lane's quad)
    float alpha[4];
#pragma unroll
    for (int r = 0; r < 4; r++) {
      float mx = fmaxf(fmaxf(sf[0][r], sf[1][r]), fmaxf(sf[2][r], sf[3][r]));
#pragma unroll
      for (int off = 1; off < 16; off <<= 1) mx = fmaxf(mx, __shfl_xor(mx, off));
      const float mn = fmaxf(mrow[r], mx);
      alpha[r] = __expf(mrow[r] - mn);
      mrow[r] = mn;
      float rs = 0.0f;
#pragma unroll
      for (int nt = 0; nt < 4; nt++) {
        const float p = __expf(sf[nt][r] - mn);
        const unsigned short pb = f2bfu(p);
        rs += bfu2f(pb);  // sum the *rounded* p so PV normalization is exact
        Ps[(wave * 16 + quad * 4 + r) * 72 + nt * 16 + l15] = pb;
      }
#pragma unroll
      for (int off = 1; off < 16; off <<= 1) rs += __shfl_xor(rs, off);
      lrow[r] = lrow[r] * alpha[r] + rs;
    }

    // rescale O
#pragma unroll
    for (int dt = 0; dt < 4; dt++)
#pragma unroll
      for (int r = 0; r < 4; r++) of[dt][r] *= alpha[r];

    __syncthreads();  // make P writes visible (guards compiler reordering too)

    // O += P V  (A = P rows of this wave, B = V^T tile)
#pragma unroll
    for (int kc = 0; kc < 2; kc++) {
      const bf16x8 ap = *(const bf16x8*)&Ps[(wave * 16 + l15) * 72 + kc * 32 + quad * 8];
#pragma unroll
      for (int dt = 0; dt < 4; dt++) {
        const bf16x8 bv = *(const bf16x8*)&Vs[(dt * 16 + l15) * 64 + kc * 32 + quad * 8];
        of[dt] = __builtin_amdgcn_mfma_f32_16x16x32_bf16(ap, bv, of[dt], 0, 0, 0);
      }
    }
  }

  // epilogue: O /= l, write bf16
#pragma unroll
  for (int r = 0; r < 4; r++) {
    const float rcp = 1.0f / lrow[r];
    const int row = tok0 + wave * 16 + quad * 4 + r;
#pragma unroll
    for (int dt = 0; dt < 4; dt++)
      Y[(size_t)row * 1024 + h * 64 + dt * 16 + l15] = __float2bfloat16(of[dt][r] * rcp);
  }
}

// ---------------- launch ----------------
extern "C" void kernel_launch(void* const* d_in, const int* in_sizes, int n_in,
                              void* d_out, int out_size, void* d_ws, size_t ws_size,
                              hipStream_t stream) {
  const float* x      = (const float*)d_in[0];
  const float* Wq     = (const float*)d_in[1];
  const float* Wk     = (const float*)d_in[2];
  const float* Wv     = (const float*)d_in[3];
  const float* Wp     = (const float*)d_in[4];
  const float* qgain  = (const float*)d_in[5];
  const float* qscale = (const float*)d_in[6];
  const float* kscale = (const float*)d_in[7];
  const float* cosb   = (const float*)d_in[8];
  const float* sinb   = (const float*)d_in[9];
  float* out = (float*)d_out;
  char* ws = (char*)d_ws;

  __hip_bfloat16* xb  = (__hip_bfloat16*)(ws);                 // 8192x1024 bf16 = 16 MiB
  __hip_bfloat16* w1b = (__hip_bfloat16*)(ws + 16777216);      // 1536x1024 bf16
  __hip_bfloat16* wpb = (__hip_bfloat16*)(ws + 19922944);      // 1024x1024 bf16
  float*          c1  = (float*)         (ws + 22020096);      // 8192x1536 f32
  __hip_bfloat16* qb  = (__hip_bfloat16*)(ws + 72351744);      // 8192x1024 bf16
  __hip_bfloat16* kb  = (__hip_bfloat16*)(ws + 89128960);      // 8192x256 bf16
  __hip_bfloat16* vtb = (__hip_bfloat16*)(ws + 93323264);      // 8x4x64x1024 bf16
  __hip_bfloat16* yb  = (__hip_bfloat16*)(ws + 97517568);      // 8192x1024 bf16

  // casts
  castk<<<8192, 256, 0, stream>>>((const float4*)x, (ushort4*)xb, 2097152);
  castk<<<1024, 256, 0, stream>>>((const float4*)Wq, (ushort4*)w1b, 262144);
  castk<<<256, 256, 0, stream>>>((const float4*)Wk, (ushort4*)(w1b + 1048576), 65536);
  castk<<<256, 256, 0, stream>>>((const float4*)Wv, (ushort4*)(w1b + 1310720), 65536);
  castk<<<1024, 256, 0, stream>>>((const float4*)Wp, (ushort4*)wpb, 262144);

  // qkv = x @ [Wq;Wk;Wv]^T
  gemm_bt<<<dim3(12, 64), 256, 0, stream>>>(xb, w1b, c1, 8192, 1536, 1024);

  // rmsnorm + rope + gain -> bf16 q,k ; transpose v -> bf16 [b][kvh][d][s]
  normrope<<<8192, 256, 0, stream>>>(c1, cosb, sinb, qgain, qscale, kscale, qb, kb);
  vtrans<<<dim3(16, 4, 8), 256, 0, stream>>>(c1, vtb);

  // flash attention
  attn<<<dim3(16, 16, 8), 256, 0, stream>>>(qb, kb, vtb, yb);

  // out = y @ Wproj^T
  gemm_bt<<<dim3(8, 64), 256, 0, stream>>>(yb, wpb, out, 8192, 1024, 1024);
}

// Round 2
// 315.098 us; speedup vs baseline: 1.1095x; 1.1095x over previous
//
#include <hip/hip_runtime.h>
#include <hip/hip_bf16.h>

// ---- constants for this problem ----
// N=8192 tokens, DIM=1024, H=16, HKV=4, HD=64, B=8, S=1024

typedef __bf16 bf16x8 __attribute__((ext_vector_type(8)));
typedef float f32x4 __attribute__((ext_vector_type(4)));

__device__ __forceinline__ void async16(const void* g, void* l) {
  __builtin_amdgcn_global_load_lds((const __attribute__((address_space(1))) void*)g,
                                   (__attribute__((address_space(3))) void*)l, 16, 0, 0);
}

__device__ __forceinline__ unsigned short f2bfu(float x) {
  __hip_bfloat16 h = __float2bfloat16(x);
  return __builtin_bit_cast(unsigned short, h);
}
__device__ __forceinline__ float bfu2f(unsigned short u) {
  return __bfloat162float(__builtin_bit_cast(__hip_bfloat16, u));
}

// ---------------- fp32 -> bf16 cast (vectorized x4) ----------------
__global__ __launch_bounds__(256) void castk(const float4* __restrict__ src,
                                             ushort4* __restrict__ dst, int n4) {
  int i = blockIdx.x * 256 + threadIdx.x;
  if (i >= n4) return;
  float4 v = src[i];
  ushort4 o;
  o.x = f2bfu(v.x); o.y = f2bfu(v.y); o.z = f2bfu(v.z); o.w = f2bfu(v.w);
  dst[i] = o;
}

// ---------------- combined weight cast: Wq|Wk|Wv -> w1b, Wp -> wpb ----------------
__global__ __launch_bounds__(256) void castw(const float4* __restrict__ Wq,
                                             const float4* __restrict__ Wk,
                                             const float4* __restrict__ Wv,
                                             const float4* __restrict__ Wp,
                                             ushort4* __restrict__ w1b,
                                             ushort4* __restrict__ wpb) {
  int i = blockIdx.x * 256 + threadIdx.x;  // float4 units; total 655360
  const float4* src;
  ushort4* dst;
  if (i < 262144)      { src = Wq + i;            dst = w1b + i; }
  else if (i < 327680) { src = Wk + (i - 262144); dst = w1b + i; }
  else if (i < 393216) { src = Wv + (i - 327680); dst = w1b + i; }
  else                 { src = Wp + (i - 393216); dst = wpb + (i - 393216); }
  float4 v = *src;
  ushort4 o;
  o.x = f2bfu(v.x); o.y = f2bfu(v.y); o.z = f2bfu(v.z); o.w = f2bfu(v.w);
  *dst = o;
}

// ---------------- NT GEMM: C[M][N] = A[M][K] * B[N][K]^T (bf16 in, f32 out) ----------------
__global__ __launch_bounds__(256) void gemm_bt(
    const __hip_bfloat16* __restrict__ A, const __hip_bfloat16* __restrict__ Bm,
    float* __restrict__ C, int M, int N, int K)
{
  __shared__ __align__(16) unsigned short As[128 * 32];
  __shared__ __align__(16) unsigned short Bs[128 * 32];
  const int tid = threadIdx.x;
  const int wave = tid >> 6, lane = tid & 63;
  const int quad = lane >> 4, l15 = lane & 15;
  const int bn = blockIdx.x, bm = blockIdx.y;
  const int wm = (wave >> 1) * 64, wn = (wave & 1) * 64;
  const int srow = lane >> 2, scol = (lane & 3) * 8;

  f32x4 acc[4][4] = {};

  const __hip_bfloat16* Ab = A + (size_t)bm * 128 * K;
  const __hip_bfloat16* Bb = Bm + (size_t)bn * 128 * K;

  for (int kt = 0; kt < K; kt += 32) {
    __syncthreads();
#pragma unroll
    for (int c = 0; c < 2; c++) {
      const int ch = wave * 2 + c;
      async16(Ab + (size_t)(ch * 16 + srow) * K + kt + scol, &As[ch * 512]);
      async16(Bb + (size_t)(ch * 16 + srow) * K + kt + scol, &Bs[ch * 512]);
    }
    __syncthreads();
    bf16x8 af[4], bfr[4];
#pragma unroll
    for (int mt = 0; mt < 4; mt++)
      af[mt] = *(const bf16x8*)&As[(wm + mt * 16 + l15) * 32 + quad * 8];
#pragma unroll
    for (int nt = 0; nt < 4; nt++)
      bfr[nt] = *(const bf16x8*)&Bs[(wn + nt * 16 + l15) * 32 + quad * 8];
#pragma unroll
    for (int mt = 0; mt < 4; mt++)
#pragma unroll
      for (int nt = 0; nt < 4; nt++)
        acc[mt][nt] = __builtin_amdgcn_mfma_f32_16x16x32_bf16(af[mt], bfr[nt], acc[mt][nt], 0, 0, 0);
  }

#pragma unroll
  for (int mt = 0; mt < 4; mt++)
#pragma unroll
    for (int nt = 0; nt < 4; nt++)
#pragma unroll
      for (int r = 0; r < 4; r++) {
        const int row = bm * 128 + wm + mt * 16 + quad * 4 + r;
        const int col = bn * 128 + wn + nt * 16 + l15;
        C[(size_t)row * N + col] = acc[mt][nt][r];
      }
}

// ---------------- per-token RMSNorm + RoPE + gain, emit bf16 Q/K ----------------
__global__ __launch_bounds__(256) void normrope(
    const float* __restrict__ c1, const float* __restrict__ cosb, const float* __restrict__ sinb,
    const float* __restrict__ qgain, const float* __restrict__ qscale, const float* __restrict__ kscale,
    __hip_bfloat16* __restrict__ Qo, __hip_bfloat16* __restrict__ Ko)
{
  const int t = blockIdx.x;
  const int wave = threadIdx.x >> 6, lane = threadIdx.x & 63;
  const float c = cosb[t * 32 + (lane & 31)];
  const float s = sinb[t * 32 + (lane & 31)];
  const float qs = qscale[0], ks = kscale[0];
  const float* row = c1 + (size_t)t * 1536;

#pragma unroll
  for (int i = 0; i < 5; i++) {
    const int h = (i < 4) ? (wave + i * 4) : wave;
    const float* src = (i < 4) ? (row + h * 64) : (row + 1024 + h * 64);
    float v = src[lane];
    float ss = v * v;
#pragma unroll
    for (int off = 1; off < 64; off <<= 1) ss += __shfl_xor(ss, off);
    const float inv = rsqrtf(ss * (1.0f / 64.0f) + 1.1920929e-07f);
    v *= inv * ((i < 4) ? qs : ks);
    const float p = __shfl_xor(v, 32);
    float r = (lane < 32) ? (v * c + p * s) : (v * c - p * s);
    if (i < 4) {
      r *= qgain[h];
      Qo[(size_t)t * 1024 + h * 64 + lane] = __float2bfloat16(r);
    } else {
      Ko[(size_t)t * 256 + h * 64 + lane] = __float2bfloat16(r);
    }
  }
}

// ---------------- transpose V slice of c1 into Vt[b][kvh][d][s] (bf16) ----------------
__global__ __launch_bounds__(256) void vtrans(const float* __restrict__ c1,
                                              __hip_bfloat16* __restrict__ Vt) {
  __shared__ float t[64][65];
  const int st = blockIdx.x, kvh = blockIdx.y, b = blockIdx.z;
  const int tid = threadIdx.x;
  const int s0 = st * 64;
#pragma unroll
  for (int i = 0; i < 16; i++) {
    const int idx = tid + i * 256;
    const int sl = idx >> 6, d = idx & 63;
    t[sl][d] = c1[(size_t)(b * 1024 + s0 + sl) * 1536 + 1280 + kvh * 64 + d];
  }
  __syncthreads();
#pragma unroll
  for (int i = 0; i < 16; i++) {
    const int idx = tid + i * 256;
    const int d = idx >> 6, sl = idx & 63;
    Vt[((size_t)(b * 4 + kvh) * 64 + d) * 1024 + s0 + sl] = __float2bfloat16(t[sl][d]);
  }
}

// ---------------- flash attention v2 ----------------
// Block = (qtile, h, b), 4 waves, 64 q-rows. One barrier per K-tile iteration.
// LDS: double-buffered K/V in split-kc layout [kc][row][32] (64B row stride ->
// 2-way bank alias = free). Q frags in registers. Wave-private P buffer
// (stride 72) read back with lgkmcnt wait only (no barrier).
__global__ __launch_bounds__(256) void attn(
    const __hip_bfloat16* __restrict__ Q,   // [N][16][64]
    const __hip_bfloat16* __restrict__ Kk,  // [N][4][64]
    const __hip_bfloat16* __restrict__ Vt,  // [8][4][64][1024]
    __hip_bfloat16* __restrict__ Y)         // [N][16][64]
{
  __shared__ __align__(16) unsigned short Kb[2][4096];  // [buf][kc*2048 + row*32 + col]
  __shared__ __align__(16) unsigned short Vb[2][4096];
  __shared__ __align__(16) unsigned short Ps[4][16 * 72];

  const int qt = 15 - blockIdx.x;           // long blocks dispatch first
  const int h = blockIdx.y, b = blockIdx.z;
  const int tid = threadIdx.x;
  const int wave = tid >> 6, lane = tid & 63;
  const int quad = lane >> 4, l15 = lane & 15;
  const int kvh = h >> 2;
  const int tok0 = b * 1024 + qt * 64;

  // staging geometry (per chunk of 1KB: 16 rows x 32 shorts)
  const int srow = lane >> 2;        // 0..15
  const int scol = (lane & 3) * 8;   // 0,8,16,24

  // Q fragments in registers (once)
  bf16x8 qf[2];
#pragma unroll
  for (int kc = 0; kc < 2; kc++)
    qf[kc] = *(const bf16x8*)(Q + (size_t)(tok0 + wave * 16 + l15) * 1024 + h * 64 + kc * 32 + quad * 8);

  // issue K/V loads for tile kt into buffer slot
  auto issue = [&](int kt, unsigned short* Ks, unsigned short* Vs) {
#pragma unroll
    for (int c = 0; c < 2; c++) {
      const int ch = wave * 2 + c;       // 0..7
      const int kc = ch >> 2, grp = ch & 3;
      // K: rows = keys
      async16(Kk + (size_t)(b * 1024 + kt * 64 + grp * 16 + srow) * 256 + kvh * 64 + kc * 32 + scol,
              Ks + kc * 2048 + grp * 512 + lane * 8);
      // V: rows = d, cols = keys of this tile
      async16(Vt + ((size_t)((b * 4 + kvh) * 64 + grp * 16 + srow)) * 1024 + kt * 64 + kc * 32 + scol,
              Vs + kc * 2048 + grp * 512 + lane * 8);
    }
  };

  issue(0, Kb[0], Vb[0]);

  f32x4 of[4] = {};
  float mrow[4], lrow[4];
#pragma unroll
  for (int r = 0; r < 4; r++) { mrow[r] = -INFINITY; lrow[r] = 0.0f; }

  const float scl = 0.125f * 1.44269504089f;  // 1/sqrt(64) * log2(e)
  unsigned short* Pw = Ps[wave];

  for (int kt = 0; kt <= qt; kt++) {
    __syncthreads();  // loads(kt) visible; all waves done reading buf (kt+1)&1
    if (kt < qt) issue(kt + 1, Kb[(kt + 1) & 1], Vb[(kt + 1) & 1]);
    const unsigned short* Ks = Kb[kt & 1];
    const unsigned short* Vs = Vb[kt & 1];

    // S = Q K^T : 16 q-rows x 64 keys per wave
    f32x4 sf[4] = {};
#pragma unroll
    for (int kc = 0; kc < 2; kc++) {
#pragma unroll
      for (int nt = 0; nt < 4; nt++) {
        const bf16x8 bk = *(const bf16x8*)&Ks[kc * 2048 + (nt * 16 + l15) * 32 + quad * 8];
        sf[nt] = __builtin_amdgcn_mfma_f32_16x16x32_bf16(qf[kc], bk, sf[nt], 0, 0, 0);
      }
    }

    // scale (base-2) + causal mask on diagonal tile
    const bool diag = (kt == qt);
#pragma unroll
    for (int nt = 0; nt < 4; nt++)
#pragma unroll
      for (int r = 0; r < 4; r++) {
        float sv = sf[nt][r] * scl;
        if (diag) {
          const int qi = wave * 16 + quad * 4 + r;
          const int ki = nt * 16 + l15;
          if (ki > qi) sv = -INFINITY;
        }
        sf[nt][r] = sv;
      }

    // online softmax (rows = quad*4+r, cols spread over l15 x nt)
    float alpha[4];
#pragma unroll
    for (int r = 0; r < 4; r++) {
      float mx = fmaxf(fmaxf(sf[0][r], sf[1][r]), fmaxf(sf[2][r], sf[3][r]));
#pragma unroll
      for (int off = 1; off < 16; off <<= 1) mx = fmaxf(mx, __shfl_xor(mx, off));
      const float mn = fmaxf(mrow[r], mx);
      alpha[r] = __builtin_amdgcn_exp2f(mrow[r] - mn);
      mrow[r] = mn;
      float rs = 0.0f;
#pragma unroll
      for (int nt = 0; nt < 4; nt++) {
        const float p = __builtin_amdgcn_exp2f(sf[nt][r] - mn);
        const unsigned short pb = f2bfu(p);
        rs += bfu2f(pb);  // sum rounded p so PV normalization cancels
        Pw[(quad * 4 + r) * 72 + nt * 16 + l15] = pb;
      }
#pragma unroll
      for (int off = 1; off < 16; off <<= 1) rs += __shfl_xor(rs, off);
      lrow[r] = lrow[r] * alpha[r] + rs;
    }

    // rescale O
#pragma unroll
    for (int dt = 0; dt < 4; dt++)
#pragma unroll
      for (int r = 0; r < 4; r++) of[dt][r] *= alpha[r];

    // wave-private P: drain LDS writes, no block barrier needed
    asm volatile("s_waitcnt lgkmcnt(0)" ::: "memory");

    // O += P V
#pragma unroll
    for (int kc = 0; kc < 2; kc++) {
      const bf16x8 ap = *(const bf16x8*)&Pw[l15 * 72 + kc * 32 + quad * 8];
#pragma unroll
      for (int dt = 0; dt < 4; dt++) {
        const bf16x8 bv = *(const bf16x8*)&Vs[kc * 2048 + (dt * 16 + l15) * 32 + quad * 8];
        of[dt] = __builtin_amdgcn_mfma_f32_16x16x32_bf16(ap, bv, of[dt], 0, 0, 0);
      }
    }
  }

  // epilogue: O /= l, write bf16
#pragma unroll
  for (int r = 0; r < 4; r++) {
    const float rcp = 1.0f / lrow[r];
    const int row = tok0 + wave * 16 + quad * 4 + r;
#pragma unroll
    for (int dt = 0; dt < 4; dt++)
      Y[(size_t)row * 1024 + h * 64 + dt * 16 + l15] = __float2bfloat16(of[dt][r] * rcp);
  }
}

// ---------------- launch ----------------
extern "C" void kernel_launch(void* const* d_in, const int* in_sizes, int n_in,
                              void* d_out, int out_size, void* d_ws, size_t ws_size,
                              hipStream_t stream) {
  const float* x      = (const float*)d_in[0];
  const float* Wq     = (const float*)d_in[1];
  const float* Wk     = (const float*)d_in[2];
  const float* Wv     = (const float*)d_in[3];
  const float* Wp     = (const float*)d_in[4];
  const float* qgain  = (const float*)d_in[5];
  const float* qscale = (const float*)d_in[6];
  const float* kscale = (const float*)d_in[7];
  const float* cosb   = (const float*)d_in[8];
  const float* sinb   = (const float*)d_in[9];
  float* out = (float*)d_out;
  char* ws = (char*)d_ws;

  __hip_bfloat16* xb  = (__hip_bfloat16*)(ws);                 // 8192x1024 bf16
  __hip_bfloat16* w1b = (__hip_bfloat16*)(ws + 16777216);      // 1536x1024 bf16
  __hip_bfloat16* wpb = (__hip_bfloat16*)(ws + 19922944);      // 1024x1024 bf16
  float*          c1  = (float*)         (ws + 22020096);      // 8192x1536 f32
  __hip_bfloat16* qb  = (__hip_bfloat16*)(ws + 72351744);      // 8192x1024 bf16
  __hip_bfloat16* kb  = (__hip_bfloat16*)(ws + 89128960);      // 8192x256 bf16
  __hip_bfloat16* vtb = (__hip_bfloat16*)(ws + 93323264);      // 8x4x64x1024 bf16
  __hip_bfloat16* yb  = (__hip_bfloat16*)(ws + 97517568);      // 8192x1024 bf16

  castk<<<8192, 256, 0, stream>>>((const float4*)x, (ushort4*)xb, 2097152);
  castw<<<2560, 256, 0, stream>>>((const float4*)Wq, (const float4*)Wk, (const float4*)Wv,
                                  (const float4*)Wp, (ushort4*)w1b, (ushort4*)wpb);

  gemm_bt<<<dim3(12, 64), 256, 0, stream>>>(xb, w1b, c1, 8192, 1536, 1024);

  normrope<<<8192, 256, 0, stream>>>(c1, cosb, sinb, qgain, qscale, kscale, qb, kb);
  vtrans<<<dim3(16, 4, 8), 256, 0, stream>>>(c1, vtb);

  attn<<<dim3(16, 16, 8), 256, 0, stream>>>(qb, kb, vtb, yb);

  gemm_bt<<<dim3(8, 64), 256, 0, stream>>>(yb, wpb, out, 8192, 1024, 1024);
}

// Round 4
// 247.342 us; speedup vs baseline: 1.4134x; 1.2739x over previous
//
#include <hip/hip_runtime.h>
#include <hip/hip_bf16.h>

// ---- constants for this problem ----
// N=8192 tokens, DIM=1024, H=16, HKV=4, HD=64, B=8, S=1024

typedef __bf16 bf16x8 __attribute__((ext_vector_type(8)));
typedef float f32x4 __attribute__((ext_vector_type(4)));

__device__ __forceinline__ void async16(const void* g, void* l) {
  __builtin_amdgcn_global_load_lds((const __attribute__((address_space(1))) void*)g,
                                   (__attribute__((address_space(3))) void*)l, 16, 0, 0);
}

__device__ __forceinline__ unsigned short f2bfu(float x) {
  __hip_bfloat16 h = __float2bfloat16(x);
  return __builtin_bit_cast(unsigned short, h);
}

// ---------------- fp32 -> bf16 cast (vectorized x4) ----------------
__global__ __launch_bounds__(256) void castk(const float4* __restrict__ src,
                                             ushort4* __restrict__ dst, int n4) {
  int i = blockIdx.x * 256 + threadIdx.x;
  if (i >= n4) return;
  float4 v = src[i];
  ushort4 o;
  o.x = f2bfu(v.x); o.y = f2bfu(v.y); o.z = f2bfu(v.z); o.w = f2bfu(v.w);
  dst[i] = o;
}

// ---------------- combined weight cast: Wq|Wk|Wv -> w1b, Wp -> wpb ----------------
__global__ __launch_bounds__(256) void castw(const float4* __restrict__ Wq,
                                             const float4* __restrict__ Wk,
                                             const float4* __restrict__ Wv,
                                             const float4* __restrict__ Wp,
                                             ushort4* __restrict__ w1b,
                                             ushort4* __restrict__ wpb) {
  int i = blockIdx.x * 256 + threadIdx.x;  // float4 units; total 655360
  const float4* src;
  ushort4* dst;
  if (i < 262144)      { src = Wq + i;            dst = w1b + i; }
  else if (i < 327680) { src = Wk + (i - 262144); dst = w1b + i; }
  else if (i < 393216) { src = Wv + (i - 327680); dst = w1b + i; }
  else                 { src = Wp + (i - 393216); dst = wpb + (i - 393216); }
  float4 v = *src;
  ushort4 o;
  o.x = f2bfu(v.x); o.y = f2bfu(v.y); o.z = f2bfu(v.z); o.w = f2bfu(v.w);
  *dst = o;
}

// ---------------- NT GEMM: C[M][N] = A[M][K] * B[N][K]^T (bf16 in, f32 out) ----------------
__global__ __launch_bounds__(256) void gemm_bt(
    const __hip_bfloat16* __restrict__ A, const __hip_bfloat16* __restrict__ Bm,
    float* __restrict__ C, int M, int N, int K)
{
  __shared__ __align__(16) unsigned short As[128 * 32];
  __shared__ __align__(16) unsigned short Bs[128 * 32];
  const int tid = threadIdx.x;
  const int wave = tid >> 6, lane = tid & 63;
  const int quad = lane >> 4, l15 = lane & 15;
  const int bn = blockIdx.x, bm = blockIdx.y;
  const int wm = (wave >> 1) * 64, wn = (wave & 1) * 64;
  const int srow = lane >> 2, scol = (lane & 3) * 8;

  f32x4 acc[4][4] = {};

  const __hip_bfloat16* Ab = A + (size_t)bm * 128 * K;
  const __hip_bfloat16* Bb = Bm + (size_t)bn * 128 * K;

  for (int kt = 0; kt < K; kt += 32) {
    __syncthreads();
#pragma unroll
    for (int c = 0; c < 2; c++) {
      const int ch = wave * 2 + c;
      async16(Ab + (size_t)(ch * 16 + srow) * K + kt + scol, &As[ch * 512]);
      async16(Bb + (size_t)(ch * 16 + srow) * K + kt + scol, &Bs[ch * 512]);
    }
    __syncthreads();
    bf16x8 af[4], bfr[4];
#pragma unroll
    for (int mt = 0; mt < 4; mt++)
      af[mt] = *(const bf16x8*)&As[(wm + mt * 16 + l15) * 32 + quad * 8];
#pragma unroll
    for (int nt = 0; nt < 4; nt++)
      bfr[nt] = *(const bf16x8*)&Bs[(wn + nt * 16 + l15) * 32 + quad * 8];
#pragma unroll
    for (int mt = 0; mt < 4; mt++)
#pragma unroll
      for (int nt = 0; nt < 4; nt++)
        acc[mt][nt] = __builtin_amdgcn_mfma_f32_16x16x32_bf16(af[mt], bfr[nt], acc[mt][nt], 0, 0, 0);
  }

#pragma unroll
  for (int mt = 0; mt < 4; mt++)
#pragma unroll
    for (int nt = 0; nt < 4; nt++)
#pragma unroll
      for (int r = 0; r < 4; r++) {
        const int row = bm * 128 + wm + mt * 16 + quad * 4 + r;
        const int col = bn * 128 + wn + nt * 16 + l15;
        C[(size_t)row * N + col] = acc[mt][nt][r];
      }
}

// ---------------- per-token RMSNorm + RoPE + gain, emit bf16 Q/K ----------------
__global__ __launch_bounds__(256) void normrope(
    const float* __restrict__ c1, const float* __restrict__ cosb, const float* __restrict__ sinb,
    const float* __restrict__ qgain, const float* __restrict__ qscale, const float* __restrict__ kscale,
    __hip_bfloat16* __restrict__ Qo, __hip_bfloat16* __restrict__ Ko)
{
  const int t = blockIdx.x;
  const int wave = threadIdx.x >> 6, lane = threadIdx.x & 63;
  const float c = cosb[t * 32 + (lane & 31)];
  const float s = sinb[t * 32 + (lane & 31)];
  const float qs = qscale[0], ks = kscale[0];
  const float* row = c1 + (size_t)t * 1536;

#pragma unroll
  for (int i = 0; i < 5; i++) {
    const int h = (i < 4) ? (wave + i * 4) : wave;
    const float* src = (i < 4) ? (row + h * 64) : (row + 1024 + h * 64);
    float v = src[lane];
    float ss = v * v;
#pragma unroll
    for (int off = 1; off < 64; off <<= 1) ss += __shfl_xor(ss, off);
    const float inv = rsqrtf(ss * (1.0f / 64.0f) + 1.1920929e-07f);
    v *= inv * ((i < 4) ? qs : ks);
    const float p = __shfl_xor(v, 32);
    float r = (lane < 32) ? (v * c + p * s) : (v * c - p * s);
    if (i < 4) {
      r *= qgain[h];
      Qo[(size_t)t * 1024 + h * 64 + lane] = __float2bfloat16(r);
    } else {
      Ko[(size_t)t * 256 + h * 64 + lane] = __float2bfloat16(r);
    }
  }
}

// ---------------- transpose V slice of c1 into Vt[b][kvh][d][s] (bf16) ----------------
__global__ __launch_bounds__(256) void vtrans(const float* __restrict__ c1,
                                              __hip_bfloat16* __restrict__ Vt) {
  __shared__ float t[64][65];
  const int st = blockIdx.x, kvh = blockIdx.y, b = blockIdx.z;
  const int tid = threadIdx.x;
  const int s0 = st * 64;
#pragma unroll
  for (int i = 0; i < 16; i++) {
    const int idx = tid + i * 256;
    const int sl = idx >> 6, d = idx & 63;
    t[sl][d] = c1[(size_t)(b * 1024 + s0 + sl) * 1536 + 1280 + kvh * 64 + d];
  }
  __syncthreads();
#pragma unroll
  for (int i = 0; i < 16; i++) {
    const int idx = tid + i * 256;
    const int d = idx >> 6, sl = idx & 63;
    Vt[((size_t)(b * 4 + kvh) * 64 + d) * 1024 + s0 + sl] = __float2bfloat16(t[sl][d]);
  }
}

// ---------------- flash attention v3.1 ----------------
// Block = (qt, kvh, b): 4 q-heads share K/V staging. 512 threads = 8 waves;
// wave w handles head kvh*4 + (w>>1), q-rows (w&1)*32 .. +32.
// Static-max softmax: scores bounded by 8 (rms-norm => ||q||=||k||=8, gain=1),
// so p = exp2(s*log2e/8) directly; no running max, no alpha rescale, l-sum is
// per-lane local (S^T layout puts softmax rows on l15) reduced once at end.
// v3.1 fix: causal mask must use the wave's global q-row (m0 offset).
__global__ __launch_bounds__(512, 4) void attn(
    const __hip_bfloat16* __restrict__ Q,   // [N][16][64]
    const __hip_bfloat16* __restrict__ Kk,  // [N][4][64]
    const __hip_bfloat16* __restrict__ Vt,  // [8][4][64][1024]
    __hip_bfloat16* __restrict__ Y)         // [N][16][64]
{
  __shared__ __align__(16) unsigned short Kb[2][4096];  // [buf][kc*2048 + key*32 + d]
  __shared__ __align__(16) unsigned short Vb[2][4096];  // [buf][kc*2048 + d*32 + key]
  __shared__ __align__(16) unsigned short Pm[8][32 * 72];  // per-wave P[m][key]
  __shared__ float Lsh[8][32];

  const int xx = blockIdx.x;
  const int qt = (xx & 1) ? (xx >> 1) : (15 - (xx >> 1));  // 15,0,14,1,... balance
  const int kvh = blockIdx.y, b = blockIdx.z;
  const int tid = threadIdx.x;
  const int wave = tid >> 6, lane = tid & 63;
  const int quad = lane >> 4, l15 = lane & 15;
  const int h = kvh * 4 + (wave >> 1);
  const int m0 = (wave & 1) * 32;
  const int tok0 = b * 1024 + qt * 64;

  const int srow = lane >> 2;        // 0..15
  const int scol = (lane & 3) * 8;   // 0,8,16,24

  // Q fragments in registers (B-operand: l15 = q-row index)
  bf16x8 qf[2][2];
#pragma unroll
  for (int mt = 0; mt < 2; mt++)
#pragma unroll
    for (int kc = 0; kc < 2; kc++)
      qf[mt][kc] = *(const bf16x8*)(Q + (size_t)(tok0 + m0 + mt * 16 + l15) * 1024 +
                                    h * 64 + kc * 32 + quad * 8);

  // issue K/V loads for tile kt (16 chunks of 1KB; wave issues 2)
  auto issue = [&](int kt, unsigned short* Ks, unsigned short* Vs) {
#pragma unroll
    for (int c = 0; c < 2; c++) {
      const int ch = wave * 2 + c;       // 0..15
      const int v = ch >> 3;             // 0: K chunk, 1: V chunk
      const int ch8 = ch & 7;
      const int kc = ch8 >> 2, grp = ch8 & 3;
      if (v == 0)
        async16(Kk + (size_t)(b * 1024 + kt * 64 + grp * 16 + srow) * 256 + kvh * 64 + kc * 32 + scol,
                Ks + kc * 2048 + grp * 512 + lane * 8);
      else
        async16(Vt + ((size_t)((b * 4 + kvh) * 64 + grp * 16 + srow)) * 1024 + kt * 64 + kc * 32 + scol,
                Vs + kc * 2048 + grp * 512 + lane * 8);
    }
  };

  issue(0, Kb[0], Vb[0]);

  f32x4 of[2][4] = {};
  float lsum[2] = {0.0f, 0.0f};
  const float scl2 = 0.125f * 1.44269504089f;
  unsigned short* Pw = Pm[wave];

  for (int kt = 0; kt <= qt; kt++) {
    __syncthreads();  // loads(kt) drained in each wave; prev buf free
    if (kt < qt) issue(kt + 1, Kb[(kt + 1) & 1], Vb[(kt + 1) & 1]);
    const unsigned short* Ks = Kb[kt & 1];
    const unsigned short* Vs = Vb[kt & 1];

    // S^T = K Q^T : C[key=quad*4+r (x4 kk)][m=l15 (x2 mt)]
    f32x4 sf[4][2] = {};
#pragma unroll
    for (int kc = 0; kc < 2; kc++) {
#pragma unroll
      for (int kk = 0; kk < 4; kk++) {
        const bf16x8 kf = *(const bf16x8*)&Ks[kc * 2048 + (kk * 16 + l15) * 32 + quad * 8];
#pragma unroll
        for (int mt = 0; mt < 2; mt++)
          sf[kk][mt] = __builtin_amdgcn_mfma_f32_16x16x32_bf16(kf, qf[mt][kc], sf[kk][mt], 0, 0, 0);
      }
    }

    // static-max softmax + pack P rows (4 consecutive keys -> one b64 store)
    const bool diag = (kt == qt);
#pragma unroll
    for (int mt = 0; mt < 2; mt++) {
#pragma unroll
      for (int kk = 0; kk < 4; kk++) {
        ushort4 pk;
        unsigned short* pp = (unsigned short*)&pk;
#pragma unroll
        for (int r = 0; r < 4; r++) {
          float p;
          // v3.1 FIX: compare against the wave's GLOBAL q-row (include m0)
          if (diag && (kk * 16 + quad * 4 + r) > (m0 + mt * 16 + l15)) {
            p = 0.0f;
          } else {
            p = __builtin_amdgcn_exp2f(sf[kk][mt][r] * scl2);
          }
          lsum[mt] += p;
          pp[r] = f2bfu(p);
        }
        *(ushort4*)&Pw[(mt * 16 + l15) * 72 + kk * 16 + quad * 4] = pk;
      }
    }

    // wave-private P: drain LDS writes only (no block barrier)
    asm volatile("s_waitcnt lgkmcnt(0)" ::: "memory");

    // O += P V : C[m=quad*4+r][d=l15]
#pragma unroll
    for (int kc = 0; kc < 2; kc++) {
#pragma unroll
      for (int mt = 0; mt < 2; mt++) {
        const bf16x8 ap = *(const bf16x8*)&Pw[(mt * 16 + l15) * 72 + kc * 32 + quad * 8];
#pragma unroll
        for (int dt = 0; dt < 4; dt++) {
          const bf16x8 bv = *(const bf16x8*)&Vs[kc * 2048 + (dt * 16 + l15) * 32 + quad * 8];
          of[mt][dt] = __builtin_amdgcn_mfma_f32_16x16x32_bf16(ap, bv, of[mt][dt], 0, 0, 0);
        }
      }
    }
  }

  // epilogue: reduce l over quads (cols were on l15), share via LDS, write O/l
#pragma unroll
  for (int mt = 0; mt < 2; mt++) {
    float l = lsum[mt];
    l += __shfl_xor(l, 16);
    l += __shfl_xor(l, 32);
    Lsh[wave][mt * 16 + l15] = l;
  }
  asm volatile("s_waitcnt lgkmcnt(0)" ::: "memory");

#pragma unroll
  for (int mt = 0; mt < 2; mt++)
#pragma unroll
    for (int r = 0; r < 4; r++) {
      const float rcp = 1.0f / Lsh[wave][mt * 16 + quad * 4 + r];
      const int row = tok0 + m0 + mt * 16 + quad * 4 + r;
#pragma unroll
      for (int dt = 0; dt < 4; dt++)
        Y[(size_t)row * 1024 + h * 64 + dt * 16 + l15] = __float2bfloat16(of[mt][dt][r] * rcp);
    }
}

// ---------------- launch ----------------
extern "C" void kernel_launch(void* const* d_in, const int* in_sizes, int n_in,
                              void* d_out, int out_size, void* d_ws, size_t ws_size,
                              hipStream_t stream) {
  const float* x      = (const float*)d_in[0];
  const float* Wq     = (const float*)d_in[1];
  const float* Wk     = (const float*)d_in[2];
  const float* Wv     = (const float*)d_in[3];
  const float* Wp     = (const float*)d_in[4];
  const float* qgain  = (const float*)d_in[5];
  const float* qscale = (const float*)d_in[6];
  const float* kscale = (const float*)d_in[7];
  const float* cosb   = (const float*)d_in[8];
  const float* sinb   = (const float*)d_in[9];
  float* out = (float*)d_out;
  char* ws = (char*)d_ws;

  __hip_bfloat16* xb  = (__hip_bfloat16*)(ws);                 // 8192x1024 bf16
  __hip_bfloat16* w1b = (__hip_bfloat16*)(ws + 16777216);      // 1536x1024 bf16
  __hip_bfloat16* wpb = (__hip_bfloat16*)(ws + 19922944);      // 1024x1024 bf16
  float*          c1  = (float*)         (ws + 22020096);      // 8192x1536 f32
  __hip_bfloat16* qb  = (__hip_bfloat16*)(ws + 72351744);      // 8192x1024 bf16
  __hip_bfloat16* kb  = (__hip_bfloat16*)(ws + 89128960);      // 8192x256 bf16
  __hip_bfloat16* vtb = (__hip_bfloat16*)(ws + 93323264);      // 8x4x64x1024 bf16
  __hip_bfloat16* yb  = (__hip_bfloat16*)(ws + 97517568);      // 8192x1024 bf16

  castk<<<8192, 256, 0, stream>>>((const float4*)x, (ushort4*)xb, 2097152);
  castw<<<2560, 256, 0, stream>>>((const float4*)Wq, (const float4*)Wk, (const float4*)Wv,
                                  (const float4*)Wp, (ushort4*)w1b, (ushort4*)wpb);

  gemm_bt<<<dim3(12, 64), 256, 0, stream>>>(xb, w1b, c1, 8192, 1536, 1024);

  normrope<<<8192, 256, 0, stream>>>(c1, cosb, sinb, qgain, qscale, kscale, qb, kb);
  vtrans<<<dim3(16, 4, 8), 256, 0, stream>>>(c1, vtb);

  attn<<<dim3(16, 4, 8), 512, 0, stream>>>(qb, kb, vtb, yb);

  gemm_bt<<<dim3(8, 64), 256, 0, stream>>>(yb, wpb, out, 8192, 1024, 1024);
}

// Round 5
// 238.474 us; speedup vs baseline: 1.4660x; 1.0372x over previous
//
#include <hip/hip_runtime.h>
#include <hip/hip_bf16.h>

// ---- constants for this problem ----
// N=8192 tokens, DIM=1024, H=16, HKV=4, HD=64, B=8, S=1024

typedef __bf16 bf16x8 __attribute__((ext_vector_type(8)));
typedef float f32x4 __attribute__((ext_vector_type(4)));

__device__ __forceinline__ void async16(const void* g, void* l) {
  __builtin_amdgcn_global_load_lds((const __attribute__((address_space(1))) void*)g,
                                   (__attribute__((address_space(3))) void*)l, 16, 0, 0);
}

__device__ __forceinline__ unsigned short f2bfu(float x) {
  __hip_bfloat16 h = __float2bfloat16(x);
  return __builtin_bit_cast(unsigned short, h);
}

// ---------------- all input casts in one kernel ----------------
// regions (float4 units): x 2097152 | Wq 262144 | Wk 65536 | Wv 65536 | Wp 262144
__global__ __launch_bounds__(256) void castall(
    const float4* __restrict__ x, const float4* __restrict__ Wq,
    const float4* __restrict__ Wk, const float4* __restrict__ Wv,
    const float4* __restrict__ Wp,
    ushort4* __restrict__ xb, ushort4* __restrict__ w1b, ushort4* __restrict__ wpb) {
  int i = blockIdx.x * 256 + threadIdx.x;  // total 2752512
  const float4* src;
  ushort4* dst;
  if (i < 2097152)      { src = x + i;             dst = xb + i; }
  else if (i < 2359296) { src = Wq + (i - 2097152); dst = w1b + (i - 2097152); }
  else if (i < 2424832) { src = Wk + (i - 2359296); dst = w1b + (i - 2097152); }
  else if (i < 2490368) { src = Wv + (i - 2424832); dst = w1b + (i - 2097152); }
  else                  { src = Wp + (i - 2490368); dst = wpb + (i - 2490368); }
  float4 v = *src;
  ushort4 o;
  o.x = f2bfu(v.x); o.y = f2bfu(v.y); o.z = f2bfu(v.z); o.w = f2bfu(v.w);
  *dst = o;
}

// ---------------- fused QKV GEMM + RMSNorm + RoPE + gain -> bf16 q/k/v ----------------
// C = x @ [Wq;Wk;Wv]^T, tile 128x128, BK=32. Each wave's 64x64 tile is exactly
// one head x 64 tokens, so norm/rope run fully in-register in the epilogue.
__global__ __launch_bounds__(256) void gemm_qkv(
    const __hip_bfloat16* __restrict__ A,   // [8192][1024] bf16
    const __hip_bfloat16* __restrict__ Bm,  // [1536][1024] bf16
    const float* __restrict__ cosb, const float* __restrict__ sinb,
    const float* __restrict__ qgain, const float* __restrict__ qscale,
    const float* __restrict__ kscale,
    __hip_bfloat16* __restrict__ Qo,  // [8192][16][64]
    __hip_bfloat16* __restrict__ Ko,  // [8192][4][64]
    __hip_bfloat16* __restrict__ Vo)  // [8192][4][64]
{
  __shared__ __align__(16) unsigned short As[128 * 32];
  __shared__ __align__(16) unsigned short Bs[128 * 32];
  const int tid = threadIdx.x;
  const int wave = tid >> 6, lane = tid & 63;
  const int quad = lane >> 4, l15 = lane & 15;
  const int bn = blockIdx.x, bm = blockIdx.y;
  const int wm = (wave >> 1) * 64, wn = (wave & 1) * 64;
  const int srow = lane >> 2, scol = (lane & 3) * 8;
  const int K = 1024;

  f32x4 acc[4][4] = {};

  const __hip_bfloat16* Ab = A + (size_t)bm * 128 * K;
  const __hip_bfloat16* Bb = Bm + (size_t)bn * 128 * K;

  for (int kt = 0; kt < K; kt += 32) {
    __syncthreads();
#pragma unroll
    for (int c = 0; c < 2; c++) {
      const int ch = wave * 2 + c;
      async16(Ab + (size_t)(ch * 16 + srow) * K + kt + scol, &As[ch * 512]);
      async16(Bb + (size_t)(ch * 16 + srow) * K + kt + scol, &Bs[ch * 512]);
    }
    __syncthreads();
    bf16x8 af[4], bfr[4];
#pragma unroll
    for (int mt = 0; mt < 4; mt++)
      af[mt] = *(const bf16x8*)&As[(wm + mt * 16 + l15) * 32 + quad * 8];
#pragma unroll
    for (int nt = 0; nt < 4; nt++)
      bfr[nt] = *(const bf16x8*)&Bs[(wn + nt * 16 + l15) * 32 + quad * 8];
#pragma unroll
    for (int mt = 0; mt < 4; mt++)
#pragma unroll
      for (int nt = 0; nt < 4; nt++)
        acc[mt][nt] = __builtin_amdgcn_mfma_f32_16x16x32_bf16(af[mt], bfr[nt], acc[mt][nt], 0, 0, 0);
  }

  // ---- fused epilogue ----
  const int hg = bn * 2 + (wn >> 6);        // global output head 0..23
  const int tokbase = bm * 128 + wm;        // wave's first token

  if (hg >= 20) {
    // V head: plain bf16 store
    const int hv = hg - 20;
#pragma unroll
    for (int mt = 0; mt < 4; mt++)
#pragma unroll
      for (int r = 0; r < 4; r++) {
        const int tok = tokbase + mt * 16 + quad * 4 + r;
#pragma unroll
        for (int nt = 0; nt < 4; nt++)
          Vo[(size_t)tok * 256 + hv * 64 + nt * 16 + l15] = __float2bfloat16(acc[mt][nt][r]);
      }
  } else {
    const bool isq = hg < 16;
    const float scale = isq ? qscale[0] : kscale[0];
    const float gain = isq ? qgain[hg] : 1.0f;  // rope is linear -> fold gain into inv
    const float sg = scale * gain;
#pragma unroll
    for (int mt = 0; mt < 4; mt++) {
      float inv[4];
#pragma unroll
      for (int r = 0; r < 4; r++) {
        float ss = acc[mt][0][r] * acc[mt][0][r] + acc[mt][1][r] * acc[mt][1][r] +
                   acc[mt][2][r] * acc[mt][2][r] + acc[mt][3][r] * acc[mt][3][r];
#pragma unroll
        for (int off = 1; off < 16; off <<= 1) ss += __shfl_xor(ss, off);
        inv[r] = rsqrtf(ss * (1.0f / 64.0f) + 1.1920929e-07f) * sg;
      }
#pragma unroll
      for (int r = 0; r < 4; r++) {
        const int tok = tokbase + mt * 16 + quad * 4 + r;
        const float c0 = cosb[tok * 32 + l15], c1 = cosb[tok * 32 + 16 + l15];
        const float s0 = sinb[tok * 32 + l15], s1 = sinb[tok * 32 + 16 + l15];
        const float v0 = acc[mt][0][r] * inv[r];
        const float v1 = acc[mt][1][r] * inv[r];
        const float v2 = acc[mt][2][r] * inv[r];
        const float v3 = acc[mt][3][r] * inv[r];
        const float o0 = v0 * c0 + v2 * s0;
        const float o1 = v1 * c1 + v3 * s1;
        const float o2 = -v0 * s0 + v2 * c0;
        const float o3 = -v1 * s1 + v3 * c1;
        __hip_bfloat16* base = isq ? (Qo + (size_t)tok * 1024 + hg * 64)
                                   : (Ko + (size_t)tok * 256 + (hg - 16) * 64);
        base[l15]      = __float2bfloat16(o0);
        base[16 + l15] = __float2bfloat16(o1);
        base[32 + l15] = __float2bfloat16(o2);
        base[48 + l15] = __float2bfloat16(o3);
      }
    }
  }
}

// ---------------- proj GEMM: out = y @ Wp^T, tile 128x64 (4 blocks/CU) ----------------
__global__ __launch_bounds__(256) void gemm_p(
    const __hip_bfloat16* __restrict__ A,   // [8192][1024] bf16
    const __hip_bfloat16* __restrict__ Bm,  // [1024][1024] bf16
    float* __restrict__ C)                  // [8192][1024] f32
{
  __shared__ __align__(16) unsigned short As[128 * 32];
  __shared__ __align__(16) unsigned short Bs[64 * 32];
  const int tid = threadIdx.x;
  const int wave = tid >> 6, lane = tid & 63;
  const int quad = lane >> 4, l15 = lane & 15;
  const int bn = blockIdx.x, bm = blockIdx.y;
  const int wm = wave * 32;                 // waves stacked in M
  const int srow = lane >> 2, scol = (lane & 3) * 8;
  const int K = 1024;

  f32x4 acc[2][4] = {};

  const __hip_bfloat16* Ab = A + (size_t)bm * 128 * K;
  const __hip_bfloat16* Bb = Bm + (size_t)bn * 64 * K;

  for (int kt = 0; kt < K; kt += 32) {
    __syncthreads();
#pragma unroll
    for (int c = 0; c < 2; c++) {
      const int ch = wave * 2 + c;
      async16(Ab + (size_t)(ch * 16 + srow) * K + kt + scol, &As[ch * 512]);
    }
    async16(Bb + (size_t)(wave * 16 + srow) * K + kt + scol, &Bs[wave * 512]);
    __syncthreads();
    bf16x8 af[2], bfr[4];
#pragma unroll
    for (int mt = 0; mt < 2; mt++)
      af[mt] = *(const bf16x8*)&As[(wm + mt * 16 + l15) * 32 + quad * 8];
#pragma unroll
    for (int nt = 0; nt < 4; nt++)
      bfr[nt] = *(const bf16x8*)&Bs[(nt * 16 + l15) * 32 + quad * 8];
#pragma unroll
    for (int mt = 0; mt < 2; mt++)
#pragma unroll
      for (int nt = 0; nt < 4; nt++)
        acc[mt][nt] = __builtin_amdgcn_mfma_f32_16x16x32_bf16(af[mt], bfr[nt], acc[mt][nt], 0, 0, 0);
  }

#pragma unroll
  for (int mt = 0; mt < 2; mt++)
#pragma unroll
    for (int nt = 0; nt < 4; nt++)
#pragma unroll
      for (int r = 0; r < 4; r++) {
        const int row = bm * 128 + wm + mt * 16 + quad * 4 + r;
        const int col = bn * 64 + nt * 16 + l15;
        C[(size_t)row * 1024 + col] = acc[mt][nt][r];
      }
}

// ---------------- transpose V (bf16 in) into Vt[b][kvh][d][s] ----------------
__global__ __launch_bounds__(256) void vtrans(const unsigned short* __restrict__ vkb,
                                              unsigned short* __restrict__ Vt) {
  __shared__ unsigned short t[64][65];
  const int st = blockIdx.x, kvh = blockIdx.y, b = blockIdx.z;
  const int tid = threadIdx.x;
  const int s0 = st * 64;
#pragma unroll
  for (int i = 0; i < 16; i++) {
    const int idx = tid + i * 256;
    const int sl = idx >> 6, d = idx & 63;
    t[sl][d] = vkb[(size_t)(b * 1024 + s0 + sl) * 256 + kvh * 64 + d];
  }
  __syncthreads();
#pragma unroll
  for (int i = 0; i < 16; i++) {
    const int idx = tid + i * 256;
    const int d = idx >> 6, sl = idx & 63;
    Vt[((size_t)(b * 4 + kvh) * 64 + d) * 1024 + s0 + sl] = t[sl][d];
  }
}

// ---------------- flash attention v3.1 (unchanged from R4) ----------------
__global__ __launch_bounds__(512, 4) void attn(
    const __hip_bfloat16* __restrict__ Q,   // [N][16][64]
    const __hip_bfloat16* __restrict__ Kk,  // [N][4][64]
    const __hip_bfloat16* __restrict__ Vt,  // [8][4][64][1024]
    __hip_bfloat16* __restrict__ Y)         // [N][16][64]
{
  __shared__ __align__(16) unsigned short Kb[2][4096];  // [buf][kc*2048 + key*32 + d]
  __shared__ __align__(16) unsigned short Vb[2][4096];  // [buf][kc*2048 + d*32 + key]
  __shared__ __align__(16) unsigned short Pm[8][32 * 72];  // per-wave P[m][key]
  __shared__ float Lsh[8][32];

  const int xx = blockIdx.x;
  const int qt = (xx & 1) ? (xx >> 1) : (15 - (xx >> 1));  // balance
  const int kvh = blockIdx.y, b = blockIdx.z;
  const int tid = threadIdx.x;
  const int wave = tid >> 6, lane = tid & 63;
  const int quad = lane >> 4, l15 = lane & 15;
  const int h = kvh * 4 + (wave >> 1);
  const int m0 = (wave & 1) * 32;
  const int tok0 = b * 1024 + qt * 64;

  const int srow = lane >> 2;
  const int scol = (lane & 3) * 8;

  bf16x8 qf[2][2];
#pragma unroll
  for (int mt = 0; mt < 2; mt++)
#pragma unroll
    for (int kc = 0; kc < 2; kc++)
      qf[mt][kc] = *(const bf16x8*)(Q + (size_t)(tok0 + m0 + mt * 16 + l15) * 1024 +
                                    h * 64 + kc * 32 + quad * 8);

  auto issue = [&](int kt, unsigned short* Ks, unsigned short* Vs) {
#pragma unroll
    for (int c = 0; c < 2; c++) {
      const int ch = wave * 2 + c;
      const int v = ch >> 3;
      const int ch8 = ch & 7;
      const int kc = ch8 >> 2, grp = ch8 & 3;
      if (v == 0)
        async16(Kk + (size_t)(b * 1024 + kt * 64 + grp * 16 + srow) * 256 + kvh * 64 + kc * 32 + scol,
                Ks + kc * 2048 + grp * 512 + lane * 8);
      else
        async16(Vt + ((size_t)((b * 4 + kvh) * 64 + grp * 16 + srow)) * 1024 + kt * 64 + kc * 32 + scol,
                Vs + kc * 2048 + grp * 512 + lane * 8);
    }
  };

  issue(0, Kb[0], Vb[0]);

  f32x4 of[2][4] = {};
  float lsum[2] = {0.0f, 0.0f};
  const float scl2 = 0.125f * 1.44269504089f;
  unsigned short* Pw = Pm[wave];

  for (int kt = 0; kt <= qt; kt++) {
    __syncthreads();
    if (kt < qt) issue(kt + 1, Kb[(kt + 1) & 1], Vb[(kt + 1) & 1]);
    const unsigned short* Ks = Kb[kt & 1];
    const unsigned short* Vs = Vb[kt & 1];

    f32x4 sf[4][2] = {};
#pragma unroll
    for (int kc = 0; kc < 2; kc++) {
#pragma unroll
      for (int kk = 0; kk < 4; kk++) {
        const bf16x8 kf = *(const bf16x8*)&Ks[kc * 2048 + (kk * 16 + l15) * 32 + quad * 8];
#pragma unroll
        for (int mt = 0; mt < 2; mt++)
          sf[kk][mt] = __builtin_amdgcn_mfma_f32_16x16x32_bf16(kf, qf[mt][kc], sf[kk][mt], 0, 0, 0);
      }
    }

    const bool diag = (kt == qt);
#pragma unroll
    for (int mt = 0; mt < 2; mt++) {
#pragma unroll
      for (int kk = 0; kk < 4; kk++) {
        ushort4 pk;
        unsigned short* pp = (unsigned short*)&pk;
#pragma unroll
        for (int r = 0; r < 4; r++) {
          float p;
          if (diag && (kk * 16 + quad * 4 + r) > (m0 + mt * 16 + l15)) {
            p = 0.0f;
          } else {
            p = __builtin_amdgcn_exp2f(sf[kk][mt][r] * scl2);
          }
          lsum[mt] += p;
          pp[r] = f2bfu(p);
        }
        *(ushort4*)&Pw[(mt * 16 + l15) * 72 + kk * 16 + quad * 4] = pk;
      }
    }

    asm volatile("s_waitcnt lgkmcnt(0)" ::: "memory");

#pragma unroll
    for (int kc = 0; kc < 2; kc++) {
#pragma unroll
      for (int mt = 0; mt < 2; mt++) {
        const bf16x8 ap = *(const bf16x8*)&Pw[(mt * 16 + l15) * 72 + kc * 32 + quad * 8];
#pragma unroll
        for (int dt = 0; dt < 4; dt++) {
          const bf16x8 bv = *(const bf16x8*)&Vs[kc * 2048 + (dt * 16 + l15) * 32 + quad * 8];
          of[mt][dt] = __builtin_amdgcn_mfma_f32_16x16x32_bf16(ap, bv, of[mt][dt], 0, 0, 0);
        }
      }
    }
  }

#pragma unroll
  for (int mt = 0; mt < 2; mt++) {
    float l = lsum[mt];
    l += __shfl_xor(l, 16);
    l += __shfl_xor(l, 32);
    Lsh[wave][mt * 16 + l15] = l;
  }
  asm volatile("s_waitcnt lgkmcnt(0)" ::: "memory");

#pragma unroll
  for (int mt = 0; mt < 2; mt++)
#pragma unroll
    for (int r = 0; r < 4; r++) {
      const float rcp = 1.0f / Lsh[wave][mt * 16 + quad * 4 + r];
      const int row = tok0 + m0 + mt * 16 + quad * 4 + r;
#pragma unroll
      for (int dt = 0; dt < 4; dt++)
        Y[(size_t)row * 1024 + h * 64 + dt * 16 + l15] = __float2bfloat16(of[mt][dt][r] * rcp);
    }
}

// ---------------- launch ----------------
extern "C" void kernel_launch(void* const* d_in, const int* in_sizes, int n_in,
                              void* d_out, int out_size, void* d_ws, size_t ws_size,
                              hipStream_t stream) {
  const float* x      = (const float*)d_in[0];
  const float* Wq     = (const float*)d_in[1];
  const float* Wk     = (const float*)d_in[2];
  const float* Wv     = (const float*)d_in[3];
  const float* Wp     = (const float*)d_in[4];
  const float* qgain  = (const float*)d_in[5];
  const float* qscale = (const float*)d_in[6];
  const float* kscale = (const float*)d_in[7];
  const float* cosb   = (const float*)d_in[8];
  const float* sinb   = (const float*)d_in[9];
  float* out = (float*)d_out;
  char* ws = (char*)d_ws;

  __hip_bfloat16* xb  = (__hip_bfloat16*)(ws);                 // 8192x1024 bf16 @0
  __hip_bfloat16* w1b = (__hip_bfloat16*)(ws + 16777216);      // 1536x1024 bf16
  __hip_bfloat16* wpb = (__hip_bfloat16*)(ws + 19922944);      // 1024x1024 bf16
  __hip_bfloat16* qb  = (__hip_bfloat16*)(ws + 22020096);      // 8192x1024 bf16
  __hip_bfloat16* kb  = (__hip_bfloat16*)(ws + 38797312);      // 8192x256 bf16
  __hip_bfloat16* vkb = (__hip_bfloat16*)(ws + 42991616);      // 8192x256 bf16
  __hip_bfloat16* vtb = (__hip_bfloat16*)(ws + 47185920);      // 8x4x64x1024 bf16
  __hip_bfloat16* yb  = (__hip_bfloat16*)(ws + 51380224);      // 8192x1024 bf16

  castall<<<10752, 256, 0, stream>>>((const float4*)x, (const float4*)Wq, (const float4*)Wk,
                                     (const float4*)Wv, (const float4*)Wp,
                                     (ushort4*)xb, (ushort4*)w1b, (ushort4*)wpb);

  gemm_qkv<<<dim3(12, 64), 256, 0, stream>>>(xb, w1b, cosb, sinb, qgain, qscale, kscale,
                                             qb, kb, vkb);

  vtrans<<<dim3(16, 4, 8), 256, 0, stream>>>((const unsigned short*)vkb, (unsigned short*)vtb);

  attn<<<dim3(16, 4, 8), 512, 0, stream>>>(qb, kb, vtb, yb);

  gemm_p<<<dim3(16, 64), 256, 0, stream>>>(yb, wpb, out);
}

// Round 6
// 220.327 us; speedup vs baseline: 1.5867x; 1.0824x over previous
//
#include <hip/hip_runtime.h>
#include <hip/hip_bf16.h>

// ---- constants for this problem ----
// N=8192 tokens, DIM=1024, H=16, HKV=4, HD=64, B=8, S=1024

typedef __bf16 bf16x8 __attribute__((ext_vector_type(8)));
typedef float f32x4 __attribute__((ext_vector_type(4)));

__device__ __forceinline__ void async16(const void* g, void* l) {
  __builtin_amdgcn_global_load_lds((const __attribute__((address_space(1))) void*)g,
                                   (__attribute__((address_space(3))) void*)l, 16, 0, 0);
}

__device__ __forceinline__ unsigned short f2bfu(float x) {
  __hip_bfloat16 h = __float2bfloat16(x);
  return __builtin_bit_cast(unsigned short, h);
}

// ---------------- all input casts in one kernel ----------------
// regions (float4 units): x 2097152 | Wq 262144 | Wk 65536 | Wv 65536 | Wp 262144
__global__ __launch_bounds__(256) void castall(
    const float4* __restrict__ x, const float4* __restrict__ Wq,
    const float4* __restrict__ Wk, const float4* __restrict__ Wv,
    const float4* __restrict__ Wp,
    ushort4* __restrict__ xb, ushort4* __restrict__ w1b, ushort4* __restrict__ wpb) {
  int i = blockIdx.x * 256 + threadIdx.x;  // total 2752512
  const float4* src;
  ushort4* dst;
  if (i < 2097152)      { src = x + i;             dst = xb + i; }
  else if (i < 2359296) { src = Wq + (i - 2097152); dst = w1b + (i - 2097152); }
  else if (i < 2424832) { src = Wk + (i - 2359296); dst = w1b + (i - 2097152); }
  else if (i < 2490368) { src = Wv + (i - 2424832); dst = w1b + (i - 2097152); }
  else                  { src = Wp + (i - 2490368); dst = wpb + (i - 2490368); }
  float4 v = *src;
  ushort4 o;
  o.x = f2bfu(v.x); o.y = f2bfu(v.y); o.z = f2bfu(v.z); o.w = f2bfu(v.w);
  *dst = o;
}

// ---------------- fused QKV GEMM + RMSNorm + RoPE + gain -> bf16 q/k/v ----------------
// C = x @ [Wq;Wk;Wv]^T, tile 128x128, BK=32. Each wave's 64x64 tile is exactly
// one head x 64 tokens, so norm/rope run fully in-register in the epilogue.
// __launch_bounds__(256,3): pin 3 blocks/CU — without it the epilogue pushes
// arch+acc VGPRs to 184 -> 2 waves/SIMD -> 2 blocks/CU (R5: 63us vs 49.6us).
__global__ __launch_bounds__(256, 3) void gemm_qkv(
    const __hip_bfloat16* __restrict__ A,   // [8192][1024] bf16
    const __hip_bfloat16* __restrict__ Bm,  // [1536][1024] bf16
    const float* __restrict__ cosb, const float* __restrict__ sinb,
    const float* __restrict__ qgain, const float* __restrict__ qscale,
    const float* __restrict__ kscale,
    __hip_bfloat16* __restrict__ Qo,  // [8192][16][64]
    __hip_bfloat16* __restrict__ Ko,  // [8192][4][64]
    __hip_bfloat16* __restrict__ Vo)  // [8192][4][64]
{
  __shared__ __align__(16) unsigned short As[128 * 32];
  __shared__ __align__(16) unsigned short Bs[128 * 32];
  const int tid = threadIdx.x;
  const int wave = tid >> 6, lane = tid & 63;
  const int quad = lane >> 4, l15 = lane & 15;
  const int bn = blockIdx.x, bm = blockIdx.y;
  const int wm = (wave >> 1) * 64, wn = (wave & 1) * 64;
  const int srow = lane >> 2, scol = (lane & 3) * 8;
  const int K = 1024;

  f32x4 acc[4][4] = {};

  const __hip_bfloat16* Ab = A + (size_t)bm * 128 * K;
  const __hip_bfloat16* Bb = Bm + (size_t)bn * 128 * K;

  for (int kt = 0; kt < K; kt += 32) {
    __syncthreads();
#pragma unroll
    for (int c = 0; c < 2; c++) {
      const int ch = wave * 2 + c;
      async16(Ab + (size_t)(ch * 16 + srow) * K + kt + scol, &As[ch * 512]);
      async16(Bb + (size_t)(ch * 16 + srow) * K + kt + scol, &Bs[ch * 512]);
    }
    __syncthreads();
    bf16x8 af[4], bfr[4];
#pragma unroll
    for (int mt = 0; mt < 4; mt++)
      af[mt] = *(const bf16x8*)&As[(wm + mt * 16 + l15) * 32 + quad * 8];
#pragma unroll
    for (int nt = 0; nt < 4; nt++)
      bfr[nt] = *(const bf16x8*)&Bs[(wn + nt * 16 + l15) * 32 + quad * 8];
#pragma unroll
    for (int mt = 0; mt < 4; mt++)
#pragma unroll
      for (int nt = 0; nt < 4; nt++)
        acc[mt][nt] = __builtin_amdgcn_mfma_f32_16x16x32_bf16(af[mt], bfr[nt], acc[mt][nt], 0, 0, 0);
  }

  // ---- fused epilogue ----
  const int hg = bn * 2 + (wn >> 6);        // global output head 0..23
  const int tokbase = bm * 128 + wm;        // wave's first token

  if (hg >= 20) {
    // V head: plain bf16 store
    const int hv = hg - 20;
#pragma unroll
    for (int mt = 0; mt < 4; mt++)
#pragma unroll
      for (int r = 0; r < 4; r++) {
        const int tok = tokbase + mt * 16 + quad * 4 + r;
#pragma unroll
        for (int nt = 0; nt < 4; nt++)
          Vo[(size_t)tok * 256 + hv * 64 + nt * 16 + l15] = __float2bfloat16(acc[mt][nt][r]);
      }
  } else {
    const bool isq = hg < 16;
    const float scale = isq ? qscale[0] : kscale[0];
    const float gain = isq ? qgain[hg] : 1.0f;  // rope is linear -> fold gain into inv
    const float sg = scale * gain;
#pragma unroll
    for (int mt = 0; mt < 4; mt++) {
      float inv[4];
#pragma unroll
      for (int r = 0; r < 4; r++) {
        float ss = acc[mt][0][r] * acc[mt][0][r] + acc[mt][1][r] * acc[mt][1][r] +
                   acc[mt][2][r] * acc[mt][2][r] + acc[mt][3][r] * acc[mt][3][r];
#pragma unroll
        for (int off = 1; off < 16; off <<= 1) ss += __shfl_xor(ss, off);
        inv[r] = rsqrtf(ss * (1.0f / 64.0f) + 1.1920929e-07f) * sg;
      }
#pragma unroll
      for (int r = 0; r < 4; r++) {
        const int tok = tokbase + mt * 16 + quad * 4 + r;
        const float c0 = cosb[tok * 32 + l15], c1 = cosb[tok * 32 + 16 + l15];
        const float s0 = sinb[tok * 32 + l15], s1 = sinb[tok * 32 + 16 + l15];
        const float v0 = acc[mt][0][r] * inv[r];
        const float v1 = acc[mt][1][r] * inv[r];
        const float v2 = acc[mt][2][r] * inv[r];
        const float v3 = acc[mt][3][r] * inv[r];
        const float o0 = v0 * c0 + v2 * s0;
        const float o1 = v1 * c1 + v3 * s1;
        const float o2 = -v0 * s0 + v2 * c0;
        const float o3 = -v1 * s1 + v3 * c1;
        __hip_bfloat16* base = isq ? (Qo + (size_t)tok * 1024 + hg * 64)
                                   : (Ko + (size_t)tok * 256 + (hg - 16) * 64);
        base[l15]      = __float2bfloat16(o0);
        base[16 + l15] = __float2bfloat16(o1);
        base[32 + l15] = __float2bfloat16(o2);
        base[48 + l15] = __float2bfloat16(o3);
      }
    }
  }
}

// ---------------- proj GEMM: out = y @ Wp^T, tile 128x64 (4 blocks/CU) ----------------
__global__ __launch_bounds__(256, 4) void gemm_p(
    const __hip_bfloat16* __restrict__ A,   // [8192][1024] bf16
    const __hip_bfloat16* __restrict__ Bm,  // [1024][1024] bf16
    float* __restrict__ C)                  // [8192][1024] f32
{
  __shared__ __align__(16) unsigned short As[128 * 32];
  __shared__ __align__(16) unsigned short Bs[64 * 32];
  const int tid = threadIdx.x;
  const int wave = tid >> 6, lane = tid & 63;
  const int quad = lane >> 4, l15 = lane & 15;
  const int bn = blockIdx.x, bm = blockIdx.y;
  const int wm = wave * 32;                 // waves stacked in M
  const int srow = lane >> 2, scol = (lane & 3) * 8;
  const int K = 1024;

  f32x4 acc[2][4] = {};

  const __hip_bfloat16* Ab = A + (size_t)bm * 128 * K;
  const __hip_bfloat16* Bb = Bm + (size_t)bn * 64 * K;

  for (int kt = 0; kt < K; kt += 32) {
    __syncthreads();
#pragma unroll
    for (int c = 0; c < 2; c++) {
      const int ch = wave * 2 + c;
      async16(Ab + (size_t)(ch * 16 + srow) * K + kt + scol, &As[ch * 512]);
    }
    async16(Bb + (size_t)(wave * 16 + srow) * K + kt + scol, &Bs[wave * 512]);
    __syncthreads();
    bf16x8 af[2], bfr[4];
#pragma unroll
    for (int mt = 0; mt < 2; mt++)
      af[mt] = *(const bf16x8*)&As[(wm + mt * 16 + l15) * 32 + quad * 8];
#pragma unroll
    for (int nt = 0; nt < 4; nt++)
      bfr[nt] = *(const bf16x8*)&Bs[(nt * 16 + l15) * 32 + quad * 8];
#pragma unroll
    for (int mt = 0; mt < 2; mt++)
#pragma unroll
      for (int nt = 0; nt < 4; nt++)
        acc[mt][nt] = __builtin_amdgcn_mfma_f32_16x16x32_bf16(af[mt], bfr[nt], acc[mt][nt], 0, 0, 0);
  }

#pragma unroll
  for (int mt = 0; mt < 2; mt++)
#pragma unroll
    for (int nt = 0; nt < 4; nt++)
#pragma unroll
      for (int r = 0; r < 4; r++) {
        const int row = bm * 128 + wm + mt * 16 + quad * 4 + r;
        const int col = bn * 64 + nt * 16 + l15;
        C[(size_t)row * 1024 + col] = acc[mt][nt][r];
      }
}

// ---------------- transpose V (bf16 in) into Vt[b][kvh][d][s] ----------------
__global__ __launch_bounds__(256) void vtrans(const unsigned short* __restrict__ vkb,
                                              unsigned short* __restrict__ Vt) {
  __shared__ unsigned short t[64][65];
  const int st = blockIdx.x, kvh = blockIdx.y, b = blockIdx.z;
  const int tid = threadIdx.x;
  const int s0 = st * 64;
#pragma unroll
  for (int i = 0; i < 16; i++) {
    const int idx = tid + i * 256;
    const int sl = idx >> 6, d = idx & 63;
    t[sl][d] = vkb[(size_t)(b * 1024 + s0 + sl) * 256 + kvh * 64 + d];
  }
  __syncthreads();
#pragma unroll
  for (int i = 0; i < 16; i++) {
    const int idx = tid + i * 256;
    const int d = idx >> 6, sl = idx & 63;
    Vt[((size_t)(b * 4 + kvh) * 64 + d) * 1024 + s0 + sl] = t[sl][d];
  }
}

// ---------------- flash attention v3.1 (unchanged) ----------------
__global__ __launch_bounds__(512, 4) void attn(
    const __hip_bfloat16* __restrict__ Q,   // [N][16][64]
    const __hip_bfloat16* __restrict__ Kk,  // [N][4][64]
    const __hip_bfloat16* __restrict__ Vt,  // [8][4][64][1024]
    __hip_bfloat16* __restrict__ Y)         // [N][16][64]
{
  __shared__ __align__(16) unsigned short Kb[2][4096];  // [buf][kc*2048 + key*32 + d]
  __shared__ __align__(16) unsigned short Vb[2][4096];  // [buf][kc*2048 + d*32 + key]
  __shared__ __align__(16) unsigned short Pm[8][32 * 72];  // per-wave P[m][key]
  __shared__ float Lsh[8][32];

  const int xx = blockIdx.x;
  const int qt = (xx & 1) ? (xx >> 1) : (15 - (xx >> 1));  // balance
  const int kvh = blockIdx.y, b = blockIdx.z;
  const int tid = threadIdx.x;
  const int wave = tid >> 6, lane = tid & 63;
  const int quad = lane >> 4, l15 = lane & 15;
  const int h = kvh * 4 + (wave >> 1);
  const int m0 = (wave & 1) * 32;
  const int tok0 = b * 1024 + qt * 64;

  const int srow = lane >> 2;
  const int scol = (lane & 3) * 8;

  bf16x8 qf[2][2];
#pragma unroll
  for (int mt = 0; mt < 2; mt++)
#pragma unroll
    for (int kc = 0; kc < 2; kc++)
      qf[mt][kc] = *(const bf16x8*)(Q + (size_t)(tok0 + m0 + mt * 16 + l15) * 1024 +
                                    h * 64 + kc * 32 + quad * 8);

  auto issue = [&](int kt, unsigned short* Ks, unsigned short* Vs) {
#pragma unroll
    for (int c = 0; c < 2; c++) {
      const int ch = wave * 2 + c;
      const int v = ch >> 3;
      const int ch8 = ch & 7;
      const int kc = ch8 >> 2, grp = ch8 & 3;
      if (v == 0)
        async16(Kk + (size_t)(b * 1024 + kt * 64 + grp * 16 + srow) * 256 + kvh * 64 + kc * 32 + scol,
                Ks + kc * 2048 + grp * 512 + lane * 8);
      else
        async16(Vt + ((size_t)((b * 4 + kvh) * 64 + grp * 16 + srow)) * 1024 + kt * 64 + kc * 32 + scol,
                Vs + kc * 2048 + grp * 512 + lane * 8);
    }
  };

  issue(0, Kb[0], Vb[0]);

  f32x4 of[2][4] = {};
  float lsum[2] = {0.0f, 0.0f};
  const float scl2 = 0.125f * 1.44269504089f;
  unsigned short* Pw = Pm[wave];

  for (int kt = 0; kt <= qt; kt++) {
    __syncthreads();
    if (kt < qt) issue(kt + 1, Kb[(kt + 1) & 1], Vb[(kt + 1) & 1]);
    const unsigned short* Ks = Kb[kt & 1];
    const unsigned short* Vs = Vb[kt & 1];

    f32x4 sf[4][2] = {};
#pragma unroll
    for (int kc = 0; kc < 2; kc++) {
#pragma unroll
      for (int kk = 0; kk < 4; kk++) {
        const bf16x8 kf = *(const bf16x8*)&Ks[kc * 2048 + (kk * 16 + l15) * 32 + quad * 8];
#pragma unroll
        for (int mt = 0; mt < 2; mt++)
          sf[kk][mt] = __builtin_amdgcn_mfma_f32_16x16x32_bf16(kf, qf[mt][kc], sf[kk][mt], 0, 0, 0);
      }
    }

    const bool diag = (kt == qt);
#pragma unroll
    for (int mt = 0; mt < 2; mt++) {
#pragma unroll
      for (int kk = 0; kk < 4; kk++) {
        ushort4 pk;
        unsigned short* pp = (unsigned short*)&pk;
#pragma unroll
        for (int r = 0; r < 4; r++) {
          float p;
          if (diag && (kk * 16 + quad * 4 + r) > (m0 + mt * 16 + l15)) {
            p = 0.0f;
          } else {
            p = __builtin_amdgcn_exp2f(sf[kk][mt][r] * scl2);
          }
          lsum[mt] += p;
          pp[r] = f2bfu(p);
        }
        *(ushort4*)&Pw[(mt * 16 + l15) * 72 + kk * 16 + quad * 4] = pk;
      }
    }

    asm volatile("s_waitcnt lgkmcnt(0)" ::: "memory");

#pragma unroll
    for (int kc = 0; kc < 2; kc++) {
#pragma unroll
      for (int mt = 0; mt < 2; mt++) {
        const bf16x8 ap = *(const bf16x8*)&Pw[(mt * 16 + l15) * 72 + kc * 32 + quad * 8];
#pragma unroll
        for (int dt = 0; dt < 4; dt++) {
          const bf16x8 bv = *(const bf16x8*)&Vs[kc * 2048 + (dt * 16 + l15) * 32 + quad * 8];
          of[mt][dt] = __builtin_amdgcn_mfma_f32_16x16x32_bf16(ap, bv, of[mt][dt], 0, 0, 0);
        }
      }
    }
  }

#pragma unroll
  for (int mt = 0; mt < 2; mt++) {
    float l = lsum[mt];
    l += __shfl_xor(l, 16);
    l += __shfl_xor(l, 32);
    Lsh[wave][mt * 16 + l15] = l;
  }
  asm volatile("s_waitcnt lgkmcnt(0)" ::: "memory");

#pragma unroll
  for (int mt = 0; mt < 2; mt++)
#pragma unroll
    for (int r = 0; r < 4; r++) {
      const float rcp = 1.0f / Lsh[wave][mt * 16 + quad * 4 + r];
      const int row = tok0 + m0 + mt * 16 + quad * 4 + r;
#pragma unroll
      for (int dt = 0; dt < 4; dt++)
        Y[(size_t)row * 1024 + h * 64 + dt * 16 + l15] = __float2bfloat16(of[mt][dt][r] * rcp);
    }
}

// ---------------- launch ----------------
extern "C" void kernel_launch(void* const* d_in, const int* in_sizes, int n_in,
                              void* d_out, int out_size, void* d_ws, size_t ws_size,
                              hipStream_t stream) {
  const float* x      = (const float*)d_in[0];
  const float* Wq     = (const float*)d_in[1];
  const float* Wk     = (const float*)d_in[2];
  const float* Wv     = (const float*)d_in[3];
  const float* Wp     = (const float*)d_in[4];
  const float* qgain  = (const float*)d_in[5];
  const float* qscale = (const float*)d_in[6];
  const float* kscale = (const float*)d_in[7];
  const float* cosb   = (const float*)d_in[8];
  const float* sinb   = (const float*)d_in[9];
  float* out = (float*)d_out;
  char* ws = (char*)d_ws;

  __hip_bfloat16* xb  = (__hip_bfloat16*)(ws);                 // 8192x1024 bf16 @0
  __hip_bfloat16* w1b = (__hip_bfloat16*)(ws + 16777216);      // 1536x1024 bf16
  __hip_bfloat16* wpb = (__hip_bfloat16*)(ws + 19922944);      // 1024x1024 bf16
  __hip_bfloat16* qb  = (__hip_bfloat16*)(ws + 22020096);      // 8192x1024 bf16
  __hip_bfloat16* kb  = (__hip_bfloat16*)(ws + 38797312);      // 8192x256 bf16
  __hip_bfloat16* vkb = (__hip_bfloat16*)(ws + 42991616);      // 8192x256 bf16
  __hip_bfloat16* vtb = (__hip_bfloat16*)(ws + 47185920);      // 8x4x64x1024 bf16
  __hip_bfloat16* yb  = (__hip_bfloat16*)(ws + 51380224);      // 8192x1024 bf16

  castall<<<10752, 256, 0, stream>>>((const float4*)x, (const float4*)Wq, (const float4*)Wk,
                                     (const float4*)Wv, (const float4*)Wp,
                                     (ushort4*)xb, (ushort4*)w1b, (ushort4*)wpb);

  gemm_qkv<<<dim3(12, 64), 256, 0, stream>>>(xb, w1b, cosb, sinb, qgain, qscale, kscale,
                                             qb, kb, vkb);

  vtrans<<<dim3(16, 4, 8), 256, 0, stream>>>((const unsigned short*)vkb, (unsigned short*)vtb);

  attn<<<dim3(16, 4, 8), 512, 0, stream>>>(qb, kb, vtb, yb);

  gemm_p<<<dim3(16, 64), 256, 0, stream>>>(yb, wpb, out);
}